// Round 14
// baseline (2884.060 us; speedup 1.0000x reference)
//
#include <hip/hip_runtime.h>
#include <math.h>

#define Bsz 16384
#define Msz 512
#define Nsz 2048

typedef _Float16 half8 __attribute__((ext_vector_type(8)));
typedef _Float16 half4 __attribute__((ext_vector_type(4)));
typedef _Float16 half2v __attribute__((ext_vector_type(2)));
typedef float floatx16 __attribute__((ext_vector_type(16)));
typedef unsigned int uint;
typedef uint uintx4 __attribute__((ext_vector_type(4)));   // clang-native: nt-load OK

struct HL { _Float16 h, l; };
__device__ __forceinline__ HL split1(float x) {
    HL r;
    r.h = (_Float16)x;
    r.l = (_Float16)(x - (float)r.h);   // exact residual (two-term split)
    return r;
}
__device__ __forceinline__ uint packHL(float x) {
    HL s = split1(x);
    return (uint)__builtin_bit_cast(unsigned short, s.h)
         | ((uint)__builtin_bit_cast(unsigned short, s.l) << 16);
}
__device__ __forceinline__ float unpackHL(uint w) {
    half2v p = __builtin_bit_cast(half2v, w);
    return (float)p.x + (float)p.y;
}

// raw barrier: no compiler-inserted vmcnt(0) drain (unlike __syncthreads).
#define BAR()  asm volatile("s_barrier" ::: "memory")

// fragment-permuted layout (32x32x16 MFMA), lane-linear:
// element (r,k) of [R][K] at frag((r>>5)*(K/16) + (k>>4))*512
//                          + ((k>>3)&1)*256 + (r&31)*8 + (k&7)      [halves]
// => lane l's half8 operand (r=l&31, k=(l>>5)*8 ..+7) sits at frag*512 + l*8:
//    a wave's 16B/lane read covers 1KB contiguous (global coalesced / LDS
//    conflict-free). Frag-row stride = K/16: 32 for K=512 planes, 128 for Dph.

// zero 19*Bsz floats (t2 slabs 1..9 + na2 slabs 0..9, contiguous)
__global__ __launch_bounds__(256) void zero_kernel(float4* __restrict__ p) {
    p[blockIdx.x * 256 + threadIdx.x] = make_float4(0.f, 0.f, 0.f, 0.f);
}

// iter-0: v = batch -> single f16 permuted plane; t2s[0][b] = sum(v^2) (fp32).
__global__ __launch_bounds__(256) void init_kernel(const float* __restrict__ batch,
        _Float16* __restrict__ vh, float* __restrict__ t2) {
    const int wave = threadIdx.x >> 6;
    const int lane = threadIdx.x & 63;
    const int b = (blockIdx.x << 2) + wave;
    const float* row = batch + (size_t)b * Msz + lane * 8;
    float4 a = *(const float4*)row;
    float4 c = *(const float4*)(row + 4);
    half8 h;
    h[0] = (_Float16)a.x; h[1] = (_Float16)a.y;
    h[2] = (_Float16)a.z; h[3] = (_Float16)a.w;
    h[4] = (_Float16)c.x; h[5] = (_Float16)c.y;
    h[6] = (_Float16)c.z; h[7] = (_Float16)c.w;
    // m = lane*8: frag col = lane>>1, (k>>3)&1 = lane&1, k&7 = 0
    const size_t off = ((size_t)(b >> 5) * 32 + (lane >> 1)) * 512
                     + ((size_t)(lane & 1) << 8) + ((b & 31) << 3);
    *(half8*)(vh + off) = h;
    float s = a.x*a.x + a.y*a.y + a.z*a.z + a.w*a.w
            + c.x*c.x + c.y*c.y + c.z*c.z + c.w*c.w;
#pragma unroll
    for (int off2 = 32; off2 > 0; off2 >>= 1) s += __shfl_down(s, off2);
    if (lane == 0) t2[b] = s;
}

// One-time: D [M][N] fp32 -> Dph  (gemm2 B: r=m, k=n, K=2048) single f16 plane
//                        and Dtph (gemm1 B: r=n, k=m, K=512)  single f16 plane
__global__ __launch_bounds__(256) void convD_kernel(const float* __restrict__ D,
        _Float16* __restrict__ Dph, _Float16* __restrict__ Dtph) {
    __shared__ float T[64][65];
    const int t = threadIdx.x;
    const int tx = t & 15, ty = t >> 4;
    const int n0 = blockIdx.x << 6, m0 = blockIdx.y << 6;
#pragma unroll
    for (int q = 0; q < 4; ++q) {
        const int mr = m0 + (ty << 2) + q;
        const int nc = n0 + (tx << 2);
        float4 d = *(const float4*)(D + (size_t)mr * Nsz + nc);
        half4 h;
        h[0] = (_Float16)d.x; h[1] = (_Float16)d.y;
        h[2] = (_Float16)d.z; h[3] = (_Float16)d.w;
        // r=mr, k=nc: frag-row stride 128 (K=2048)
        const size_t o2 = ((size_t)(mr >> 5) * 128 + (nc >> 4)) * 512
                        + (((size_t)(nc >> 3) & 1) << 8) + ((mr & 31) << 3) + (nc & 7);
        *(half4*)(Dph + o2) = h;
        T[(tx << 2) + 0][(ty << 2) + q] = d.x;
        T[(tx << 2) + 1][(ty << 2) + q] = d.y;
        T[(tx << 2) + 2][(ty << 2) + q] = d.z;
        T[(tx << 2) + 3][(ty << 2) + q] = d.w;
    }
    __syncthreads();
#pragma unroll
    for (int q = 0; q < 4; ++q) {
        const int nr = n0 + (ty << 2) + q;
        const int mc = m0 + (tx << 2);
        float4 d = make_float4(T[(ty << 2) + q][tx << 2],
                               T[(ty << 2) + q][(tx << 2) + 1],
                               T[(ty << 2) + q][(tx << 2) + 2],
                               T[(ty << 2) + q][(tx << 2) + 3]);
        half4 h;
        h[0] = (_Float16)d.x; h[1] = (_Float16)d.y;
        h[2] = (_Float16)d.z; h[3] = (_Float16)d.w;
        // r=nr, k=mc: frag-row stride 32 (K=512)
        const size_t o1 = ((size_t)(nr >> 5) * 32 + (mc >> 4)) * 512
                        + (((size_t)(mc >> 3) & 1) << 8) + ((nr & 31) << 3) + (mc & 7);
        *(half4*)(Dtph + o1) = h;
    }
}

// gemm1: alpha = relu((FIRST?0:alpha) + beta*(v@D) - t[b]); fused na2 atomic.
// NO-LDS variant (R11, proven 107->92 us). R14: alpha RMW uses NON-TEMPORAL
// loads/stores so the 273MB/dispatch alpha stream stops evicting Dt+v from
// L2 (per-XCD: Dt 2MB + v-slice 2MB = exactly L2 size); K-loop load latency
// drops toward L2-hit and the 1-deep prefetch + 4-wave TLP can cover it.
template<int FIRST, int LAST>
__global__ __launch_bounds__(256, 4) void gemm1_kernel(
        const _Float16* __restrict__ Av,
        const _Float16* __restrict__ Bth,
        const float* __restrict__ t2,
        uint* __restrict__ alphaP,
        float* __restrict__ na2,
        const float* __restrict__ beta_p, const float* __restrict__ gamma_p) {
    const int tid = threadIdx.x;
    const int wave = tid >> 6, lane = tid & 63;
    const int wy = wave >> 1, wx = wave & 1;     // 2x2 wave grid
    const int ln = lane & 31, lh = lane >> 5;
    const int bid = blockIdx.x;
    const int b0 = (bid & 127) << 7;             // 128 row-tiles of 128
    const int n0 = (bid >> 7) << 7;              // 16 col-tiles of 128
    const int R0 = b0 >> 5, C0 = n0 >> 5;

    floatx16 acc[2][2] = {};

    // per-wave frag base pointers (frag-row stride 32, K=512 planes)
    const _Float16* pa0 = Av  + ((size_t)(R0 + 2 * wy)     * 32) * 512 + lane * 8;
    const _Float16* pa1 = Av  + ((size_t)(R0 + 2 * wy + 1) * 32) * 512 + lane * 8;
    const _Float16* pb0 = Bth + ((size_t)(C0 + 2 * wx)     * 32) * 512 + lane * 8;
    const _Float16* pb1 = Bth + ((size_t)(C0 + 2 * wx + 1) * 32) * 512 + lane * 8;

    // two named register banks; explicit 2-step unroll keeps indexing static
    half8 xa0, xa1, xb0, xb1;    // bank X (even kt)
    half8 ya0, ya1, yb0, yb1;    // bank Y (odd kt)

    xa0 = *(const half8*)(pa0);
    xa1 = *(const half8*)(pa1);
    xb0 = *(const half8*)(pb0);
    xb1 = *(const half8*)(pb1);

    for (int kt = 0; kt < 32; kt += 2) {
        {   // prefetch kt+1 into bank Y, compute kt from bank X
            const size_t o = (size_t)(kt + 1) << 9;
            ya0 = *(const half8*)(pa0 + o);
            ya1 = *(const half8*)(pa1 + o);
            yb0 = *(const half8*)(pb0 + o);
            yb1 = *(const half8*)(pb1 + o);
            acc[0][0] = __builtin_amdgcn_mfma_f32_32x32x16_f16(xa0, xb0, acc[0][0], 0, 0, 0);
            acc[1][0] = __builtin_amdgcn_mfma_f32_32x32x16_f16(xa1, xb0, acc[1][0], 0, 0, 0);
            acc[0][1] = __builtin_amdgcn_mfma_f32_32x32x16_f16(xa0, xb1, acc[0][1], 0, 0, 0);
            acc[1][1] = __builtin_amdgcn_mfma_f32_32x32x16_f16(xa1, xb1, acc[1][1], 0, 0, 0);
        }
        {   // prefetch kt+2 into bank X, compute kt+1 from bank Y
            if (kt + 2 < 32) {
                const size_t o = (size_t)(kt + 2) << 9;
                xa0 = *(const half8*)(pa0 + o);
                xa1 = *(const half8*)(pa1 + o);
                xb0 = *(const half8*)(pb0 + o);
                xb1 = *(const half8*)(pb1 + o);
            }
            acc[0][0] = __builtin_amdgcn_mfma_f32_32x32x16_f16(ya0, yb0, acc[0][0], 0, 0, 0);
            acc[1][0] = __builtin_amdgcn_mfma_f32_32x32x16_f16(ya1, yb0, acc[1][0], 0, 0, 0);
            acc[0][1] = __builtin_amdgcn_mfma_f32_32x32x16_f16(ya0, yb1, acc[0][1], 0, 0, 0);
            acc[1][1] = __builtin_amdgcn_mfma_f32_32x32x16_f16(ya1, yb1, acc[1][1], 0, 0, 0);
        }
    }

    const float beta = beta_p[0];
    const float tc = gamma_p[0] * 0.044194173824159216f;   // gamma / sqrt(512)
#pragma unroll
    for (int i = 0; i < 2; ++i) {
#pragma unroll
        for (int reg = 0; reg < 16; ++reg) {
            const int rr = (reg & 3) + 8 * (reg >> 2) + 4 * lh;   // 0..31
            const int b = b0 + wy * 64 + i * 32 + rr;
            const float tb2 = tc * sqrtf(t2[b]);
            uint* arow = alphaP + (size_t)b * Nsz + n0 + wx * 64 + ln;
            float s = 0.f;
#pragma unroll
            for (int j = 0; j < 2; ++j) {
                float z = FIRST ? 0.f
                                : unpackHL(__builtin_nontemporal_load(arow + j * 32));
                float val = fmaxf(fmaf(beta, acc[i][j][reg], z) - tb2, 0.f);
                if (LAST) __builtin_nontemporal_store(val, (float*)arow + j * 32);
                else      __builtin_nontemporal_store(packHL(val), arow + j * 32);
                s = fmaf(val, val, s);
            }
            s += __shfl_down(s, 16, 32);
            s += __shfl_down(s, 8, 32);
            s += __shfl_down(s, 4, 32);
            s += __shfl_down(s, 2, 32);
            s += __shfl_down(s, 1, 32);
            if (ln == 0) atomicAdd(&na2[b], s);
        }
    }
}

// gemm2: v = y - beta*(alpha@D^T) + beta/512*sqrt(na2[b])*v_old; fused t2 atomic.
// 128x128 tile, 4 waves (2x2), grid 512 = 2 blocks/CU. B (Dph, L2-resident)
// direct global->VGPR, named-bank prefetch; A reg->ds_write (16KB dbuf), one
// raw barrier/chunk. R14: A-stream (alpha) and y reads NON-TEMPORAL so Dph
// stays L2-resident against the 166MB/dispatch streaming traffic.
__global__ __launch_bounds__(256, 2) void gemm2_kernel(
        const uint* __restrict__ alphaP,
        const _Float16* __restrict__ Bh,
        const float* __restrict__ na2,
        const float* __restrict__ y,
        _Float16* __restrict__ vh,
        float* __restrict__ t2,
        const float* __restrict__ beta_p) {
    __shared__ _Float16 lds[8192];    // 16KB: 2 x (A frags 0..7)

    const int tid = threadIdx.x;
    const int wave = tid >> 6, lane = tid & 63;
    const int wy = wave >> 1, wx = wave & 1;
    const int ln = lane & 31, lh = lane >> 5;
    const int bid = blockIdx.x;
    const int b0 = (bid & 127) << 7;             // 128 row-tiles of 128
    const int m0 = (bid >> 7) << 7;              // 4 col-tiles of 128
    const int C0 = m0 >> 5;

    floatx16 acc[2][2] = {};

    // A staging: thread (srow, skq) covers one ktile-half of one row (16 words)
    const int srow = tid >> 1;                   // 0..127
    const int skq  = (tid & 1) << 4;
    const uint* apP = alphaP + (size_t)(b0 + srow) * Nsz + skq;
    // frag f = rowsub*2 + ktile; lane-linear: k&15 in 0..7 -> +0, 8..15 -> +256
    const int awo = ((((srow >> 5) << 1) + (skq >> 4)) << 9) + ((srow & 31) << 3);

    // B direct-load frag pointers (Dph frag-row stride = K/16 = 128)
    const _Float16* pb0 = Bh + ((size_t)(C0 + 2 * wx)     * 128) * 512 + lane * 8;
    const _Float16* pb1 = Bh + ((size_t)(C0 + 2 * wx + 1) * 128) * 512 + lane * 8;

    const int ro = lane << 3;

    uintx4 a0, a1, a2, a3;     // ext_vector uint4: nontemporal builtin accepts it
    auto loadA = [&](int c) {
        const uint* nx = apP + c * 32;
        a0 = __builtin_nontemporal_load((const uintx4*)(nx));
        a1 = __builtin_nontemporal_load((const uintx4*)(nx + 4));
        a2 = __builtin_nontemporal_load((const uintx4*)(nx + 8));
        a3 = __builtin_nontemporal_load((const uintx4*)(nx + 12));
    };
    auto writeA = [&](int d) {      // extract hi (low16s) and ds_write in frag format
        uintx4 ha, hb;
        ha.x = __builtin_amdgcn_perm(a0.y, a0.x, 0x05040100u);
        ha.y = __builtin_amdgcn_perm(a0.w, a0.z, 0x05040100u);
        ha.z = __builtin_amdgcn_perm(a1.y, a1.x, 0x05040100u);
        ha.w = __builtin_amdgcn_perm(a1.w, a1.z, 0x05040100u);
        hb.x = __builtin_amdgcn_perm(a2.y, a2.x, 0x05040100u);
        hb.y = __builtin_amdgcn_perm(a2.w, a2.z, 0x05040100u);
        hb.z = __builtin_amdgcn_perm(a3.y, a3.x, 0x05040100u);
        hb.w = __builtin_amdgcn_perm(a3.w, a3.z, 0x05040100u);
        _Float16* aw = lds + d * 4096 + awo;
        *(uintx4*)aw = ha;
        *(uintx4*)(aw + 256) = hb;
    };

    // B banks (named registers, static indexing)
    half8 xb0, xb1, yb0, yb1;

    // prologue: buf0 = A(0); regs hold A(1); bank X = B(kt=0)
    loadA(0);
    writeA(0);            // auto vm-wait for loadA(0) regs
    loadA(1);
    xb0 = *(const half8*)(pb0);
    xb1 = *(const half8*)(pb1);
    asm volatile("s_waitcnt lgkmcnt(0)" ::: "memory");
    BAR();                // buf0 published; loadA(1)+bankX stay in flight

    for (int c = 0; c < 64; ++c) {
        const _Float16* lb = lds + (c & 1) * 4096;
        // ks = 0 (global kt = 2c): prefetch bank Y (kt = 2c+1), compute bank X
        {
            const size_t o = ((size_t)(2 * c + 1)) << 9;
            yb0 = *(const half8*)(pb0 + o);
            yb1 = *(const half8*)(pb1 + o);
            half8 fa0 = *(const half8*)(lb + ((((wy * 2 + 0) << 1) + 0) << 9) + ro);
            half8 fa1 = *(const half8*)(lb + ((((wy * 2 + 1) << 1) + 0) << 9) + ro);
            acc[0][0] = __builtin_amdgcn_mfma_f32_32x32x16_f16(fa0, xb0, acc[0][0], 0, 0, 0);
            acc[1][0] = __builtin_amdgcn_mfma_f32_32x32x16_f16(fa1, xb0, acc[1][0], 0, 0, 0);
            acc[0][1] = __builtin_amdgcn_mfma_f32_32x32x16_f16(fa0, xb1, acc[0][1], 0, 0, 0);
            acc[1][1] = __builtin_amdgcn_mfma_f32_32x32x16_f16(fa1, xb1, acc[1][1], 0, 0, 0);
        }
        // ks = 1 (global kt = 2c+1): prefetch bank X (kt = 2c+2), compute bank Y
        {
            if (c < 63) {
                const size_t o = ((size_t)(2 * c + 2)) << 9;
                xb0 = *(const half8*)(pb0 + o);
                xb1 = *(const half8*)(pb1 + o);
            }
            half8 fa0 = *(const half8*)(lb + ((((wy * 2 + 0) << 1) + 1) << 9) + ro);
            half8 fa1 = *(const half8*)(lb + ((((wy * 2 + 1) << 1) + 1) << 9) + ro);
            acc[0][0] = __builtin_amdgcn_mfma_f32_32x32x16_f16(fa0, yb0, acc[0][0], 0, 0, 0);
            acc[1][0] = __builtin_amdgcn_mfma_f32_32x32x16_f16(fa1, yb0, acc[1][0], 0, 0, 0);
            acc[0][1] = __builtin_amdgcn_mfma_f32_32x32x16_f16(fa0, yb1, acc[0][1], 0, 0, 0);
            acc[1][1] = __builtin_amdgcn_mfma_f32_32x32x16_f16(fa1, yb1, acc[1][1], 0, 0, 0);
        }
        if (c == 63) break;
        // tail: publish A(c+1) into buf[(c+1)&1], start loadA(c+2)
        writeA((c + 1) & 1);              // auto vm-wait: loadA(c+1) regs ready
        if (c < 62) loadA(c + 2);
        asm volatile("s_waitcnt lgkmcnt(0)" ::: "memory");   // my ds_write+ds_read done
        BAR();                            // buf[(c+1)&1] published to all waves
    }

    const float beta = beta_p[0];
#pragma unroll
    for (int i = 0; i < 2; ++i) {
#pragma unroll
        for (int reg = 0; reg < 16; ++reg) {
            const int rr = (reg & 3) + 8 * (reg >> 2) + 4 * lh;
            const int b = b0 + wy * 64 + i * 32 + rr;
            const float cb = beta * (1.0f / 512.0f) * sqrtf(na2[b]);
            float s = 0.f;
#pragma unroll
            for (int j = 0; j < 2; ++j) {
                const int m = m0 + wx * 64 + j * 32 + ln;
                const size_t po = ((size_t)(b >> 5) * 32 + (m >> 4)) * 512
                                + (((size_t)(m >> 3) & 1) << 8) + ((b & 31) << 3) + (m & 7);
                const size_t yi = (size_t)b * Msz + m;
                float vold = (float)vh[po];
                float yv = __builtin_nontemporal_load(y + yi);
                float val = yv - beta * acc[i][j][reg] + cb * vold;
                vh[po] = (_Float16)val;
                s = fmaf(val, val, s);
            }
            s += __shfl_down(s, 16, 32);
            s += __shfl_down(s, 8, 32);
            s += __shfl_down(s, 4, 32);
            s += __shfl_down(s, 2, 32);
            s += __shfl_down(s, 1, 32);
            if (ln == 0) atomicAdd(&t2[b], s);
        }
    }
}

extern "C" void kernel_launch(void* const* d_in, const int* in_sizes, int n_in,
                              void* d_out, int out_size, void* d_ws, size_t ws_size,
                              hipStream_t stream) {
    (void)in_sizes; (void)n_in; (void)out_size; (void)ws_size;
    const float* batch   = (const float*)d_in[0];   // [B, M]
    const float* D       = (const float*)d_in[1];   // [M, N]
    const float* gamma_p = (const float*)d_in[2];   // scalar
    const float* beta_p  = (const float*)d_in[3];   // scalar

    uint* alphaP = (uint*)d_out;    // packed hi/lo per element (plain layout); fp32 after final iter

    // workspace (~22 MB)
    _Float16* vh   = (_Float16*)d_ws;               // [B*M] permuted, single plane
    _Float16* Dph  = vh + (size_t)Bsz * Msz;        // [M*N] permuted (gemm2 B), f16
    _Float16* Dtph = Dph + (size_t)Msz * Nsz;       // [N*M] permuted (gemm1 B), f16
    float*    t2s  = (float*)(Dtph + (size_t)Msz * Nsz);   // [10][Bsz] sum v^2
    float*    na2s = t2s + 10 * Bsz;                        // [10][Bsz] sum alpha^2

    // zero t2 slabs 1..9 + na2 slabs 0..9 (contiguous 19*Bsz floats)
    zero_kernel<<<19 * Bsz / 1024, 256, 0, stream>>>((float4*)(t2s + Bsz));
    convD_kernel<<<dim3(Nsz / 64, Msz / 64), 256, 0, stream>>>(D, Dph, Dtph);
    init_kernel<<<Bsz / 4, 256, 0, stream>>>(batch, vh, t2s);   // writes t2 slab 0

    for (int it = 0; it < 10; ++it) {
        if (it == 0)
            gemm1_kernel<1, 0><<<2048, 256, 0, stream>>>(vh, Dtph,
                    t2s + (size_t)it * Bsz, alphaP, na2s + (size_t)it * Bsz,
                    beta_p, gamma_p);
        else if (it == 9)
            gemm1_kernel<0, 1><<<2048, 256, 0, stream>>>(vh, Dtph,
                    t2s + (size_t)it * Bsz, alphaP, na2s + (size_t)it * Bsz,
                    beta_p, gamma_p);
        else
            gemm1_kernel<0, 0><<<2048, 256, 0, stream>>>(vh, Dtph,
                    t2s + (size_t)it * Bsz, alphaP, na2s + (size_t)it * Bsz,
                    beta_p, gamma_p);
        if (it < 9) {   // last iteration's new_v is unused by the reference output
            gemm2_kernel<<<512, 256, 0, stream>>>(alphaP, Dph,
                                                  na2s + (size_t)it * Bsz,
                                                  batch, vh,
                                                  t2s + (size_t)(it + 1) * Bsz,
                                                  beta_p);
        }
    }
}

// Round 15
// 1645.811 us; speedup vs baseline: 1.7524x; 1.7524x over previous
//
#include <hip/hip_runtime.h>
#include <math.h>

#define Bsz 16384
#define Msz 512
#define Nsz 2048

typedef _Float16 half8 __attribute__((ext_vector_type(8)));
typedef _Float16 half4 __attribute__((ext_vector_type(4)));
typedef _Float16 half2v __attribute__((ext_vector_type(2)));
typedef float floatx16 __attribute__((ext_vector_type(16)));
typedef unsigned int uint;

struct HL { _Float16 h, l; };
__device__ __forceinline__ HL split1(float x) {
    HL r;
    r.h = (_Float16)x;
    r.l = (_Float16)(x - (float)r.h);   // exact residual (two-term split)
    return r;
}
__device__ __forceinline__ uint packHL(float x) {
    HL s = split1(x);
    return (uint)__builtin_bit_cast(unsigned short, s.h)
         | ((uint)__builtin_bit_cast(unsigned short, s.l) << 16);
}
__device__ __forceinline__ float unpackHL(uint w) {
    half2v p = __builtin_bit_cast(half2v, w);
    return (float)p.x + (float)p.y;
}

// async global->LDS, 16B per lane. LDS dest = wave-uniform base + lane*16.
__device__ __forceinline__ void gl_lds16(const _Float16* g, _Float16* l) {
    __builtin_amdgcn_global_load_lds(
        (const __attribute__((address_space(1))) unsigned int*)g,
        (__attribute__((address_space(3))) unsigned int*)l, 16, 0, 0);
}

// raw barrier: no compiler-inserted vmcnt(0) drain (unlike __syncthreads).
#define BAR()  asm volatile("s_barrier" ::: "memory")

// fragment-permuted layout (32x32x16 MFMA), lane-linear:
// element (r,k) of [R][K] at frag((r>>5)*(K/16) + (k>>4))*512
//                          + ((k>>3)&1)*256 + (r&31)*8 + (k&7)      [halves]
// => lane l's half8 operand (r=l&31, k=(l>>5)*8 ..+7) sits at frag*512 + l*8:
//    a wave's 16B/lane read covers 1KB contiguous (global coalesced / LDS
//    conflict-free). Frag-row stride = K/16: 32 for K=512 planes, 128 for Dph.

// zero 19*Bsz floats (t2 slabs 1..9 + na2 slabs 0..9, contiguous)
__global__ __launch_bounds__(256) void zero_kernel(float4* __restrict__ p) {
    p[blockIdx.x * 256 + threadIdx.x] = make_float4(0.f, 0.f, 0.f, 0.f);
}

// iter-0: v = batch -> single f16 permuted plane; t2s[0][b] = sum(v^2) (fp32).
__global__ __launch_bounds__(256) void init_kernel(const float* __restrict__ batch,
        _Float16* __restrict__ vh, float* __restrict__ t2) {
    const int wave = threadIdx.x >> 6;
    const int lane = threadIdx.x & 63;
    const int b = (blockIdx.x << 2) + wave;
    const float* row = batch + (size_t)b * Msz + lane * 8;
    float4 a = *(const float4*)row;
    float4 c = *(const float4*)(row + 4);
    half8 h;
    h[0] = (_Float16)a.x; h[1] = (_Float16)a.y;
    h[2] = (_Float16)a.z; h[3] = (_Float16)a.w;
    h[4] = (_Float16)c.x; h[5] = (_Float16)c.y;
    h[6] = (_Float16)c.z; h[7] = (_Float16)c.w;
    // m = lane*8: frag col = lane>>1, (k>>3)&1 = lane&1, k&7 = 0
    const size_t off = ((size_t)(b >> 5) * 32 + (lane >> 1)) * 512
                     + ((size_t)(lane & 1) << 8) + ((b & 31) << 3);
    *(half8*)(vh + off) = h;
    float s = a.x*a.x + a.y*a.y + a.z*a.z + a.w*a.w
            + c.x*c.x + c.y*c.y + c.z*c.z + c.w*c.w;
#pragma unroll
    for (int off2 = 32; off2 > 0; off2 >>= 1) s += __shfl_down(s, off2);
    if (lane == 0) t2[b] = s;
}

// One-time: D [M][N] fp32 -> Dph  (gemm2 B: r=m, k=n, K=2048) single f16 plane
//                        and Dtph (gemm1 B: r=n, k=m, K=512)  single f16 plane
__global__ __launch_bounds__(256) void convD_kernel(const float* __restrict__ D,
        _Float16* __restrict__ Dph, _Float16* __restrict__ Dtph) {
    __shared__ float T[64][65];
    const int t = threadIdx.x;
    const int tx = t & 15, ty = t >> 4;
    const int n0 = blockIdx.x << 6, m0 = blockIdx.y << 6;
#pragma unroll
    for (int q = 0; q < 4; ++q) {
        const int mr = m0 + (ty << 2) + q;
        const int nc = n0 + (tx << 2);
        float4 d = *(const float4*)(D + (size_t)mr * Nsz + nc);
        half4 h;
        h[0] = (_Float16)d.x; h[1] = (_Float16)d.y;
        h[2] = (_Float16)d.z; h[3] = (_Float16)d.w;
        // r=mr, k=nc: frag-row stride 128 (K=2048)
        const size_t o2 = ((size_t)(mr >> 5) * 128 + (nc >> 4)) * 512
                        + (((size_t)(nc >> 3) & 1) << 8) + ((mr & 31) << 3) + (nc & 7);
        *(half4*)(Dph + o2) = h;
        T[(tx << 2) + 0][(ty << 2) + q] = d.x;
        T[(tx << 2) + 1][(ty << 2) + q] = d.y;
        T[(tx << 2) + 2][(ty << 2) + q] = d.z;
        T[(tx << 2) + 3][(ty << 2) + q] = d.w;
    }
    __syncthreads();
#pragma unroll
    for (int q = 0; q < 4; ++q) {
        const int nr = n0 + (ty << 2) + q;
        const int mc = m0 + (tx << 2);
        float4 d = make_float4(T[(ty << 2) + q][tx << 2],
                               T[(ty << 2) + q][(tx << 2) + 1],
                               T[(ty << 2) + q][(tx << 2) + 2],
                               T[(ty << 2) + q][(tx << 2) + 3]);
        half4 h;
        h[0] = (_Float16)d.x; h[1] = (_Float16)d.y;
        h[2] = (_Float16)d.z; h[3] = (_Float16)d.w;
        // r=nr, k=mc: frag-row stride 32 (K=512)
        const size_t o1 = ((size_t)(nr >> 5) * 32 + (mc >> 4)) * 512
                        + (((size_t)(mc >> 3) & 1) << 8) + ((nr & 31) << 3) + (mc & 7);
        *(half4*)(Dtph + o1) = h;
    }
}

// gemm1: alpha = relu((FIRST?0:alpha) + beta*(v@D) - t[b]); fused na2 atomic.
// NO-LDS variant (R11, proven 107->92 us): both operands cache-resident,
// direct global->VGPR frag loads, double-banked kt-prefetch, zero barriers.
template<int FIRST, int LAST>
__global__ __launch_bounds__(256, 4) void gemm1_kernel(
        const _Float16* __restrict__ Av,
        const _Float16* __restrict__ Bth,
        const float* __restrict__ t2,
        uint* __restrict__ alphaP,
        float* __restrict__ na2,
        const float* __restrict__ beta_p, const float* __restrict__ gamma_p) {
    const int tid = threadIdx.x;
    const int wave = tid >> 6, lane = tid & 63;
    const int wy = wave >> 1, wx = wave & 1;     // 2x2 wave grid
    const int ln = lane & 31, lh = lane >> 5;
    const int bid = blockIdx.x;
    const int b0 = (bid & 127) << 7;             // 128 row-tiles of 128
    const int n0 = (bid >> 7) << 7;              // 16 col-tiles of 128
    const int R0 = b0 >> 5, C0 = n0 >> 5;

    floatx16 acc[2][2] = {};

    // per-wave frag base pointers (frag-row stride 32, K=512 planes)
    const _Float16* pa0 = Av  + ((size_t)(R0 + 2 * wy)     * 32) * 512 + lane * 8;
    const _Float16* pa1 = Av  + ((size_t)(R0 + 2 * wy + 1) * 32) * 512 + lane * 8;
    const _Float16* pb0 = Bth + ((size_t)(C0 + 2 * wx)     * 32) * 512 + lane * 8;
    const _Float16* pb1 = Bth + ((size_t)(C0 + 2 * wx + 1) * 32) * 512 + lane * 8;

    // two named register banks; explicit 2-step unroll keeps indexing static
    half8 xa0, xa1, xb0, xb1;    // bank X (even kt)
    half8 ya0, ya1, yb0, yb1;    // bank Y (odd kt)

    xa0 = *(const half8*)(pa0);
    xa1 = *(const half8*)(pa1);
    xb0 = *(const half8*)(pb0);
    xb1 = *(const half8*)(pb1);

    for (int kt = 0; kt < 32; kt += 2) {
        {   // prefetch kt+1 into bank Y, compute kt from bank X
            const size_t o = (size_t)(kt + 1) << 9;
            ya0 = *(const half8*)(pa0 + o);
            ya1 = *(const half8*)(pa1 + o);
            yb0 = *(const half8*)(pb0 + o);
            yb1 = *(const half8*)(pb1 + o);
            acc[0][0] = __builtin_amdgcn_mfma_f32_32x32x16_f16(xa0, xb0, acc[0][0], 0, 0, 0);
            acc[1][0] = __builtin_amdgcn_mfma_f32_32x32x16_f16(xa1, xb0, acc[1][0], 0, 0, 0);
            acc[0][1] = __builtin_amdgcn_mfma_f32_32x32x16_f16(xa0, xb1, acc[0][1], 0, 0, 0);
            acc[1][1] = __builtin_amdgcn_mfma_f32_32x32x16_f16(xa1, xb1, acc[1][1], 0, 0, 0);
        }
        {   // prefetch kt+2 into bank X, compute kt+1 from bank Y
            if (kt + 2 < 32) {
                const size_t o = (size_t)(kt + 2) << 9;
                xa0 = *(const half8*)(pa0 + o);
                xa1 = *(const half8*)(pa1 + o);
                xb0 = *(const half8*)(pb0 + o);
                xb1 = *(const half8*)(pb1 + o);
            }
            acc[0][0] = __builtin_amdgcn_mfma_f32_32x32x16_f16(ya0, yb0, acc[0][0], 0, 0, 0);
            acc[1][0] = __builtin_amdgcn_mfma_f32_32x32x16_f16(ya1, yb0, acc[1][0], 0, 0, 0);
            acc[0][1] = __builtin_amdgcn_mfma_f32_32x32x16_f16(ya0, yb1, acc[0][1], 0, 0, 0);
            acc[1][1] = __builtin_amdgcn_mfma_f32_32x32x16_f16(ya1, yb1, acc[1][1], 0, 0, 0);
        }
    }

    const float beta = beta_p[0];
    const float tc = gamma_p[0] * 0.044194173824159216f;   // gamma / sqrt(512)
#pragma unroll
    for (int i = 0; i < 2; ++i) {
#pragma unroll
        for (int reg = 0; reg < 16; ++reg) {
            const int rr = (reg & 3) + 8 * (reg >> 2) + 4 * lh;   // 0..31
            const int b = b0 + wy * 64 + i * 32 + rr;
            const float tb2 = tc * sqrtf(t2[b]);
            uint* arow = alphaP + (size_t)b * Nsz + n0 + wx * 64 + ln;
            float s = 0.f;
#pragma unroll
            for (int j = 0; j < 2; ++j) {
                float z = FIRST ? 0.f : unpackHL(arow[j * 32]);
                float val = fmaxf(fmaf(beta, acc[i][j][reg], z) - tb2, 0.f);
                if (LAST) ((float*)arow)[j * 32] = val;   // final fp32, same 4-B slot
                else      arow[j * 32] = packHL(val);
                s = fmaf(val, val, s);
            }
            s += __shfl_down(s, 16, 32);
            s += __shfl_down(s, 8, 32);
            s += __shfl_down(s, 4, 32);
            s += __shfl_down(s, 2, 32);
            s += __shfl_down(s, 1, 32);
            if (ln == 0) atomicAdd(&na2[b], s);
        }
    }
}

// gemm2: v = y - beta*(alpha@D^T) + beta/512*sqrt(na2[b])*v_old; fused t2 atomic.
// 128x128 tile, 4 waves (2x2), grid 512 = 2 blocks/CU. Double-buffered 32KB,
// counted vmcnt (never 0 mid-loop), raw barriers. A = alpha_hi regs
// (load c+3, write c+2); B via gl_lds (2 frags/wave). R10-proven variant.
__global__ __launch_bounds__(256, 2) void gemm2_kernel(
        const uint* __restrict__ alphaP,
        const _Float16* __restrict__ Bh,
        const float* __restrict__ na2,
        const float* __restrict__ y,
        _Float16* __restrict__ vh,
        float* __restrict__ t2,
        const float* __restrict__ beta_p) {
    __shared__ _Float16 lds[16384];   // 32KB: 2 x (A frags 0..7 | B frags 8..15)

    const int tid = threadIdx.x;
    const int wave = tid >> 6, lane = tid & 63;
    const int wy = wave >> 1, wx = wave & 1;
    const int ln = lane & 31, lh = lane >> 5;
    const int bid = blockIdx.x;
    const int b0 = (bid & 127) << 7;             // 128 row-tiles of 128
    const int m0 = (bid >> 7) << 7;              // 4 col-tiles of 128
    const int C0 = m0 >> 5;

    floatx16 acc[2][2] = {};

    // A staging: thread (srow, skq) covers one ktile-half of one row (16 words)
    const int srow = tid >> 1;                   // 0..127
    const int skq  = (tid & 1) << 4;
    const uint* apP = alphaP + (size_t)(b0 + srow) * Nsz + skq;
    // lane-linear frag layout: k&15 in 0..7 -> +0, 8..15 -> +256
    const int awo = ((((srow >> 5) << 1) + (skq >> 4)) << 9) + ((srow & 31) << 3);

    // B staging via gl_lds: wave w stages B subtile C0+w, both ktiles.
    // Dph frag-row stride = K/16 = 128 (K=2048).
    const _Float16* gB = Bh + ((size_t)(C0 + wave) * 128) * 512 + lane * 8;
    const int fB = 8 + wave * 2;

    const int ro = lane << 3;

    uint4 a0, a1, a2, a3;
    auto loadA = [&](int c) {
        const uint* nx = apP + c * 32;
        a0 = *(const uint4*)(nx);
        a1 = *(const uint4*)(nx + 4);
        a2 = *(const uint4*)(nx + 8);
        a3 = *(const uint4*)(nx + 12);
    };
    auto writeA = [&](int d) {      // extract hi (low16s) and ds_write in frag format
        uint4 ha, hb;
        ha.x = __builtin_amdgcn_perm(a0.y, a0.x, 0x05040100u);
        ha.y = __builtin_amdgcn_perm(a0.w, a0.z, 0x05040100u);
        ha.z = __builtin_amdgcn_perm(a1.y, a1.x, 0x05040100u);
        ha.w = __builtin_amdgcn_perm(a1.w, a1.z, 0x05040100u);
        hb.x = __builtin_amdgcn_perm(a2.y, a2.x, 0x05040100u);
        hb.y = __builtin_amdgcn_perm(a2.w, a2.z, 0x05040100u);
        hb.z = __builtin_amdgcn_perm(a3.y, a3.x, 0x05040100u);
        hb.w = __builtin_amdgcn_perm(a3.w, a3.z, 0x05040100u);
        _Float16* aw = lds + d * 8192 + awo;
        *(uint4*)aw = ha;
        *(uint4*)(aw + 256) = hb;
    };
    auto stageB = [&](int c, int d) {
        _Float16* lB = lds + d * 8192;
#pragma unroll
        for (int kt = 0; kt < 2; ++kt)
            gl_lds16(gB + (size_t)kt * 512 + (size_t)c * 1024, lB + ((fB + kt) << 9));
    };

    // prologue: buf0 complete; buf1 B in flight + A written; regs hold A(2)
    loadA(0);
    writeA(0);
    stageB(0, 0);
    loadA(1);
    writeA(1);            // implicit vmcnt wait drains loadA(1) (and stageB(0))
    stageB(1, 1);
    loadA(2);
    asm volatile("s_waitcnt vmcnt(6) lgkmcnt(0)" ::: "memory");
    BAR();

    for (int c = 0; c < 64; ++c) {
        const _Float16* lb = lds + (c & 1) * 8192;
        __builtin_amdgcn_s_setprio(1);
#pragma unroll
        for (int ks = 0; ks < 2; ++ks) {
            half8 fa[2], fb[2];
#pragma unroll
            for (int i = 0; i < 2; ++i) {
                fa[i] = *(const half8*)(lb + ((((wy * 2 + i) << 1) + ks) << 9) + ro);
                fb[i] = *(const half8*)(lb + 4096 + ((((wx * 2 + i) << 1) + ks) << 9) + ro);
            }
#pragma unroll
            for (int j = 0; j < 2; ++j)
#pragma unroll
                for (int i = 0; i < 2; ++i)
                    acc[i][j] = __builtin_amdgcn_mfma_f32_32x32x16_f16(fa[i], fb[j], acc[i][j], 0, 0, 0);
        }
        __builtin_amdgcn_s_setprio(0);
        if (c == 63) break;
        BAR();                           // readers of buf[c&1] done
        if (c < 61) {
            stageB(c + 2, c & 1);        // B(c+2) flies across barriers
            writeA(c & 1);               // A(c+2); implicit wait drains loadA(c+2)
            loadA(c + 3);                // A regs for next chunk's writeA
            asm volatile("s_waitcnt vmcnt(6) lgkmcnt(0)" ::: "memory");
        } else if (c == 61) {
            stageB(63, 1);
            writeA(1);                   // A(63) from loadA(63) (issued at c=60)
            asm volatile("s_waitcnt vmcnt(2) lgkmcnt(0)" ::: "memory");
        } else {                         // c == 62: drain stageB(63)
            asm volatile("s_waitcnt vmcnt(0) lgkmcnt(0)" ::: "memory");
        }
        BAR();                           // buf[(c+1)&1] published
    }

    const float beta = beta_p[0];
#pragma unroll
    for (int i = 0; i < 2; ++i) {
#pragma unroll
        for (int reg = 0; reg < 16; ++reg) {
            const int rr = (reg & 3) + 8 * (reg >> 2) + 4 * lh;
            const int b = b0 + wy * 64 + i * 32 + rr;
            const float cb = beta * (1.0f / 512.0f) * sqrtf(na2[b]);
            float s = 0.f;
#pragma unroll
            for (int j = 0; j < 2; ++j) {
                const int m = m0 + wx * 64 + j * 32 + ln;
                const size_t po = ((size_t)(b >> 5) * 32 + (m >> 4)) * 512
                                + (((size_t)(m >> 3) & 1) << 8) + ((b & 31) << 3) + (m & 7);
                const size_t yi = (size_t)b * Msz + m;
                float vold = (float)vh[po];
                float val = y[yi] - beta * acc[i][j][reg] + cb * vold;
                vh[po] = (_Float16)val;
                s = fmaf(val, val, s);
            }
            s += __shfl_down(s, 16, 32);
            s += __shfl_down(s, 8, 32);
            s += __shfl_down(s, 4, 32);
            s += __shfl_down(s, 2, 32);
            s += __shfl_down(s, 1, 32);
            if (ln == 0) atomicAdd(&t2[b], s);
        }
    }
}

extern "C" void kernel_launch(void* const* d_in, const int* in_sizes, int n_in,
                              void* d_out, int out_size, void* d_ws, size_t ws_size,
                              hipStream_t stream) {
    (void)in_sizes; (void)n_in; (void)out_size; (void)ws_size;
    const float* batch   = (const float*)d_in[0];   // [B, M]
    const float* D       = (const float*)d_in[1];   // [M, N]
    const float* gamma_p = (const float*)d_in[2];   // scalar
    const float* beta_p  = (const float*)d_in[3];   // scalar

    uint* alphaP = (uint*)d_out;    // packed hi/lo per element (plain layout); fp32 after final iter

    // workspace (~22 MB)
    _Float16* vh   = (_Float16*)d_ws;               // [B*M] permuted, single plane
    _Float16* Dph  = vh + (size_t)Bsz * Msz;        // [M*N] permuted (gemm2 B), f16
    _Float16* Dtph = Dph + (size_t)Msz * Nsz;       // [N*M] permuted (gemm1 B), f16
    float*    t2s  = (float*)(Dtph + (size_t)Msz * Nsz);   // [10][Bsz] sum v^2
    float*    na2s = t2s + 10 * Bsz;                        // [10][Bsz] sum alpha^2

    // zero t2 slabs 1..9 + na2 slabs 0..9 (contiguous 19*Bsz floats)
    zero_kernel<<<19 * Bsz / 1024, 256, 0, stream>>>((float4*)(t2s + Bsz));
    convD_kernel<<<dim3(Nsz / 64, Msz / 64), 256, 0, stream>>>(D, Dph, Dtph);
    init_kernel<<<Bsz / 4, 256, 0, stream>>>(batch, vh, t2s);   // writes t2 slab 0

    for (int it = 0; it < 10; ++it) {
        if (it == 0)
            gemm1_kernel<1, 0><<<2048, 256, 0, stream>>>(vh, Dtph,
                    t2s + (size_t)it * Bsz, alphaP, na2s + (size_t)it * Bsz,
                    beta_p, gamma_p);
        else if (it == 9)
            gemm1_kernel<0, 1><<<2048, 256, 0, stream>>>(vh, Dtph,
                    t2s + (size_t)it * Bsz, alphaP, na2s + (size_t)it * Bsz,
                    beta_p, gamma_p);
        else
            gemm1_kernel<0, 0><<<2048, 256, 0, stream>>>(vh, Dtph,
                    t2s + (size_t)it * Bsz, alphaP, na2s + (size_t)it * Bsz,
                    beta_p, gamma_p);
        if (it < 9) {   // last iteration's new_v is unused by the reference output
            gemm2_kernel<<<512, 256, 0, stream>>>(alphaP, Dph,
                                                  na2s + (size_t)it * Bsz,
                                                  batch, vh,
                                                  t2s + (size_t)(it + 1) * Bsz,
                                                  beta_p);
        }
    }
}

// Round 16
// 1562.861 us; speedup vs baseline: 1.8454x; 1.0531x over previous
//
#include <hip/hip_runtime.h>
#include <math.h>

#define Bsz 16384
#define Msz 512
#define Nsz 2048

typedef _Float16 half8 __attribute__((ext_vector_type(8)));
typedef _Float16 half4 __attribute__((ext_vector_type(4)));
typedef _Float16 half2v __attribute__((ext_vector_type(2)));
typedef float floatx16 __attribute__((ext_vector_type(16)));
typedef unsigned int uint;

// async global->LDS, 16B per lane. LDS dest = wave-uniform base + lane*16.
__device__ __forceinline__ void gl_lds16(const _Float16* g, _Float16* l) {
    __builtin_amdgcn_global_load_lds(
        (const __attribute__((address_space(1))) unsigned int*)g,
        (__attribute__((address_space(3))) unsigned int*)l, 16, 0, 0);
}

// raw barrier: no compiler-inserted vmcnt(0) drain (unlike __syncthreads).
#define BAR()  asm volatile("s_barrier" ::: "memory")

// fragment-permuted layout (32x32x16 MFMA), lane-linear:
// element (r,k) of [R][K] at frag((r>>5)*(K/16) + (k>>4))*512
//                          + ((k>>3)&1)*256 + (r&31)*8 + (k&7)      [halves]
// => lane l's half8 operand (r=l&31, k=(l>>5)*8 ..+7) sits at frag*512 + l*8:
//    a wave's 16B/lane read covers 1KB contiguous (global coalesced / LDS
//    conflict-free). Frag-row stride = K/16: 32 for K=512 planes, 128 for Dph.
//
// R16: alpha carried as PLAIN f16 [B][N] (2B/elem) — halves the dominant
// alpha RMW stream (gemm1 273->137 MB/dispatch, gemm2 A-read 134->67).
// gemm2 already consumed only the hi half; only gemm1's carry loses ~11 bits.
// Final iteration writes fp32 plain to d_out (alphaH untouched that pass).

// zero 19*Bsz floats (t2 slabs 1..9 + na2 slabs 0..9, contiguous)
__global__ __launch_bounds__(256) void zero_kernel(float4* __restrict__ p) {
    p[blockIdx.x * 256 + threadIdx.x] = make_float4(0.f, 0.f, 0.f, 0.f);
}

// iter-0: v = batch -> single f16 permuted plane; t2s[0][b] = sum(v^2) (fp32).
__global__ __launch_bounds__(256) void init_kernel(const float* __restrict__ batch,
        _Float16* __restrict__ vh, float* __restrict__ t2) {
    const int wave = threadIdx.x >> 6;
    const int lane = threadIdx.x & 63;
    const int b = (blockIdx.x << 2) + wave;
    const float* row = batch + (size_t)b * Msz + lane * 8;
    float4 a = *(const float4*)row;
    float4 c = *(const float4*)(row + 4);
    half8 h;
    h[0] = (_Float16)a.x; h[1] = (_Float16)a.y;
    h[2] = (_Float16)a.z; h[3] = (_Float16)a.w;
    h[4] = (_Float16)c.x; h[5] = (_Float16)c.y;
    h[6] = (_Float16)c.z; h[7] = (_Float16)c.w;
    // m = lane*8: frag col = lane>>1, (k>>3)&1 = lane&1, k&7 = 0
    const size_t off = ((size_t)(b >> 5) * 32 + (lane >> 1)) * 512
                     + ((size_t)(lane & 1) << 8) + ((b & 31) << 3);
    *(half8*)(vh + off) = h;
    float s = a.x*a.x + a.y*a.y + a.z*a.z + a.w*a.w
            + c.x*c.x + c.y*c.y + c.z*c.z + c.w*c.w;
#pragma unroll
    for (int off2 = 32; off2 > 0; off2 >>= 1) s += __shfl_down(s, off2);
    if (lane == 0) t2[b] = s;
}

// One-time: D [M][N] fp32 -> Dph  (gemm2 B: r=m, k=n, K=2048) single f16 plane
//                        and Dtph (gemm1 B: r=n, k=m, K=512)  single f16 plane
__global__ __launch_bounds__(256) void convD_kernel(const float* __restrict__ D,
        _Float16* __restrict__ Dph, _Float16* __restrict__ Dtph) {
    __shared__ float T[64][65];
    const int t = threadIdx.x;
    const int tx = t & 15, ty = t >> 4;
    const int n0 = blockIdx.x << 6, m0 = blockIdx.y << 6;
#pragma unroll
    for (int q = 0; q < 4; ++q) {
        const int mr = m0 + (ty << 2) + q;
        const int nc = n0 + (tx << 2);
        float4 d = *(const float4*)(D + (size_t)mr * Nsz + nc);
        half4 h;
        h[0] = (_Float16)d.x; h[1] = (_Float16)d.y;
        h[2] = (_Float16)d.z; h[3] = (_Float16)d.w;
        // r=mr, k=nc: frag-row stride 128 (K=2048)
        const size_t o2 = ((size_t)(mr >> 5) * 128 + (nc >> 4)) * 512
                        + (((size_t)(nc >> 3) & 1) << 8) + ((mr & 31) << 3) + (nc & 7);
        *(half4*)(Dph + o2) = h;
        T[(tx << 2) + 0][(ty << 2) + q] = d.x;
        T[(tx << 2) + 1][(ty << 2) + q] = d.y;
        T[(tx << 2) + 2][(ty << 2) + q] = d.z;
        T[(tx << 2) + 3][(ty << 2) + q] = d.w;
    }
    __syncthreads();
#pragma unroll
    for (int q = 0; q < 4; ++q) {
        const int nr = n0 + (ty << 2) + q;
        const int mc = m0 + (tx << 2);
        float4 d = make_float4(T[(ty << 2) + q][tx << 2],
                               T[(ty << 2) + q][(tx << 2) + 1],
                               T[(ty << 2) + q][(tx << 2) + 2],
                               T[(ty << 2) + q][(tx << 2) + 3]);
        half4 h;
        h[0] = (_Float16)d.x; h[1] = (_Float16)d.y;
        h[2] = (_Float16)d.z; h[3] = (_Float16)d.w;
        // r=nr, k=mc: frag-row stride 32 (K=512)
        const size_t o1 = ((size_t)(nr >> 5) * 32 + (mc >> 4)) * 512
                        + (((size_t)(mc >> 3) & 1) << 8) + ((nr & 31) << 3) + (mc & 7);
        *(half4*)(Dtph + o1) = h;
    }
}

// gemm1: alpha = relu((FIRST?0:alpha) + beta*(v@D) - t[b]); fused na2 atomic.
// NO-LDS variant (proven 92 us): both operands cache-resident, direct
// global->VGPR frag loads, double-banked kt-prefetch, zero barriers.
// R16: alpha carried as plain f16 (halved RMW); LAST writes fp32 to out.
template<int FIRST, int LAST>
__global__ __launch_bounds__(256, 4) void gemm1_kernel(
        const _Float16* __restrict__ Av,
        const _Float16* __restrict__ Bth,
        const float* __restrict__ t2,
        _Float16* __restrict__ alphaH,
        float* __restrict__ out,
        float* __restrict__ na2,
        const float* __restrict__ beta_p, const float* __restrict__ gamma_p) {
    const int tid = threadIdx.x;
    const int wave = tid >> 6, lane = tid & 63;
    const int wy = wave >> 1, wx = wave & 1;     // 2x2 wave grid
    const int ln = lane & 31, lh = lane >> 5;
    const int bid = blockIdx.x;
    const int b0 = (bid & 127) << 7;             // 128 row-tiles of 128
    const int n0 = (bid >> 7) << 7;              // 16 col-tiles of 128
    const int R0 = b0 >> 5, C0 = n0 >> 5;

    floatx16 acc[2][2] = {};

    // per-wave frag base pointers (frag-row stride 32, K=512 planes)
    const _Float16* pa0 = Av  + ((size_t)(R0 + 2 * wy)     * 32) * 512 + lane * 8;
    const _Float16* pa1 = Av  + ((size_t)(R0 + 2 * wy + 1) * 32) * 512 + lane * 8;
    const _Float16* pb0 = Bth + ((size_t)(C0 + 2 * wx)     * 32) * 512 + lane * 8;
    const _Float16* pb1 = Bth + ((size_t)(C0 + 2 * wx + 1) * 32) * 512 + lane * 8;

    // two named register banks; explicit 2-step unroll keeps indexing static
    half8 xa0, xa1, xb0, xb1;    // bank X (even kt)
    half8 ya0, ya1, yb0, yb1;    // bank Y (odd kt)

    xa0 = *(const half8*)(pa0);
    xa1 = *(const half8*)(pa1);
    xb0 = *(const half8*)(pb0);
    xb1 = *(const half8*)(pb1);

    for (int kt = 0; kt < 32; kt += 2) {
        {   // prefetch kt+1 into bank Y, compute kt from bank X
            const size_t o = (size_t)(kt + 1) << 9;
            ya0 = *(const half8*)(pa0 + o);
            ya1 = *(const half8*)(pa1 + o);
            yb0 = *(const half8*)(pb0 + o);
            yb1 = *(const half8*)(pb1 + o);
            acc[0][0] = __builtin_amdgcn_mfma_f32_32x32x16_f16(xa0, xb0, acc[0][0], 0, 0, 0);
            acc[1][0] = __builtin_amdgcn_mfma_f32_32x32x16_f16(xa1, xb0, acc[1][0], 0, 0, 0);
            acc[0][1] = __builtin_amdgcn_mfma_f32_32x32x16_f16(xa0, xb1, acc[0][1], 0, 0, 0);
            acc[1][1] = __builtin_amdgcn_mfma_f32_32x32x16_f16(xa1, xb1, acc[1][1], 0, 0, 0);
        }
        {   // prefetch kt+2 into bank X, compute kt+1 from bank Y
            if (kt + 2 < 32) {
                const size_t o = (size_t)(kt + 2) << 9;
                xa0 = *(const half8*)(pa0 + o);
                xa1 = *(const half8*)(pa1 + o);
                xb0 = *(const half8*)(pb0 + o);
                xb1 = *(const half8*)(pb1 + o);
            }
            acc[0][0] = __builtin_amdgcn_mfma_f32_32x32x16_f16(ya0, yb0, acc[0][0], 0, 0, 0);
            acc[1][0] = __builtin_amdgcn_mfma_f32_32x32x16_f16(ya1, yb0, acc[1][0], 0, 0, 0);
            acc[0][1] = __builtin_amdgcn_mfma_f32_32x32x16_f16(ya0, yb1, acc[0][1], 0, 0, 0);
            acc[1][1] = __builtin_amdgcn_mfma_f32_32x32x16_f16(ya1, yb1, acc[1][1], 0, 0, 0);
        }
    }

    const float beta = beta_p[0];
    const float tc = gamma_p[0] * 0.044194173824159216f;   // gamma / sqrt(512)
#pragma unroll
    for (int i = 0; i < 2; ++i) {
#pragma unroll
        for (int reg = 0; reg < 16; ++reg) {
            const int rr = (reg & 3) + 8 * (reg >> 2) + 4 * lh;   // 0..31
            const int b = b0 + wy * 64 + i * 32 + rr;
            const float tb2 = tc * sqrtf(t2[b]);
            const size_t rbase = (size_t)b * Nsz + n0 + wx * 64 + ln;
            _Float16* arow = alphaH + rbase;
            float s = 0.f;
#pragma unroll
            for (int j = 0; j < 2; ++j) {
                float z = FIRST ? 0.f : (float)arow[j * 32];
                float val = fmaxf(fmaf(beta, acc[i][j][reg], z) - tb2, 0.f);
                if (LAST) out[rbase + j * 32] = val;   // final fp32, plain layout
                else      arow[j * 32] = (_Float16)val;
                s = fmaf(val, val, s);
            }
            s += __shfl_down(s, 16, 32);
            s += __shfl_down(s, 8, 32);
            s += __shfl_down(s, 4, 32);
            s += __shfl_down(s, 2, 32);
            s += __shfl_down(s, 1, 32);
            if (ln == 0) atomicAdd(&na2[b], s);
        }
    }
}

// gemm2: v = y - beta*(alpha@D^T) + beta/512*sqrt(na2[b])*v_old; fused t2 atomic.
// 128x128 tile, 4 waves (2x2), grid 512 = 2 blocks/CU. Double-buffered 32KB,
// counted vmcnt (never 0 mid-loop), raw barriers. A = plain-f16 alpha regs
// (load c+3, write c+2; raw 16-half copy, no perms); B via gl_lds (2 frags/wave).
__global__ __launch_bounds__(256, 2) void gemm2_kernel(
        const _Float16* __restrict__ alphaH,
        const _Float16* __restrict__ Bh,
        const float* __restrict__ na2,
        const float* __restrict__ y,
        _Float16* __restrict__ vh,
        float* __restrict__ t2,
        const float* __restrict__ beta_p) {
    __shared__ _Float16 lds[16384];   // 32KB: 2 x (A frags 0..7 | B frags 8..15)

    const int tid = threadIdx.x;
    const int wave = tid >> 6, lane = tid & 63;
    const int wy = wave >> 1, wx = wave & 1;
    const int ln = lane & 31, lh = lane >> 5;
    const int bid = blockIdx.x;
    const int b0 = (bid & 127) << 7;             // 128 row-tiles of 128
    const int m0 = (bid >> 7) << 7;              // 4 col-tiles of 128
    const int C0 = m0 >> 5;

    floatx16 acc[2][2] = {};

    // A staging: thread (srow, skq) covers one ktile-half of one row (16 halves)
    const int srow = tid >> 1;                   // 0..127
    const int skq  = (tid & 1) << 4;
    const _Float16* apP = alphaH + (size_t)(b0 + srow) * Nsz + skq;
    // lane-linear frag layout: k&15 in 0..7 -> +0, 8..15 -> +256
    const int awo = ((((srow >> 5) << 1) + (skq >> 4)) << 9) + ((srow & 31) << 3);

    // B staging via gl_lds: wave w stages B subtile C0+w, both ktiles.
    // Dph frag-row stride = K/16 = 128 (K=2048).
    const _Float16* gB = Bh + ((size_t)(C0 + wave) * 128) * 512 + lane * 8;
    const int fB = 8 + wave * 2;

    const int ro = lane << 3;

    uint4 a0, a1;                 // 32B = 16 halves of plain f16 alpha
    auto loadA = [&](int c) {
        const _Float16* nx = apP + c * 32;
        a0 = *(const uint4*)(nx);
        a1 = *(const uint4*)(nx + 8);
    };
    auto writeA = [&](int d) {    // raw copy into frag format (no extraction)
        _Float16* aw = lds + d * 8192 + awo;
        *(uint4*)aw = a0;
        *(uint4*)(aw + 256) = a1;
    };
    auto stageB = [&](int c, int d) {
        _Float16* lB = lds + d * 8192;
#pragma unroll
        for (int kt = 0; kt < 2; ++kt)
            gl_lds16(gB + (size_t)kt * 512 + (size_t)c * 1024, lB + ((fB + kt) << 9));
    };

    // prologue: buf0 complete; buf1 B in flight + A written; regs hold A(2)
    loadA(0);
    writeA(0);
    stageB(0, 0);
    loadA(1);
    writeA(1);            // implicit vmcnt wait drains loadA(1) (and stageB(0))
    stageB(1, 1);
    loadA(2);
    asm volatile("s_waitcnt vmcnt(6) lgkmcnt(0)" ::: "memory");
    BAR();

    for (int c = 0; c < 64; ++c) {
        const _Float16* lb = lds + (c & 1) * 8192;
        __builtin_amdgcn_s_setprio(1);
#pragma unroll
        for (int ks = 0; ks < 2; ++ks) {
            half8 fa[2], fb[2];
#pragma unroll
            for (int i = 0; i < 2; ++i) {
                fa[i] = *(const half8*)(lb + ((((wy * 2 + i) << 1) + ks) << 9) + ro);
                fb[i] = *(const half8*)(lb + 4096 + ((((wx * 2 + i) << 1) + ks) << 9) + ro);
            }
#pragma unroll
            for (int j = 0; j < 2; ++j)
#pragma unroll
                for (int i = 0; i < 2; ++i)
                    acc[i][j] = __builtin_amdgcn_mfma_f32_32x32x16_f16(fa[i], fb[j], acc[i][j], 0, 0, 0);
        }
        __builtin_amdgcn_s_setprio(0);
        if (c == 63) break;
        BAR();                           // readers of buf[c&1] done
        if (c < 61) {
            stageB(c + 2, c & 1);        // B(c+2) flies across barriers
            writeA(c & 1);               // A(c+2); implicit wait drains loadA(c+2)
            loadA(c + 3);                // A regs for next chunk's writeA
            asm volatile("s_waitcnt vmcnt(6) lgkmcnt(0)" ::: "memory");
        } else if (c == 61) {
            stageB(63, 1);
            writeA(1);                   // A(63) from loadA(63) (issued at c=60)
            asm volatile("s_waitcnt vmcnt(2) lgkmcnt(0)" ::: "memory");
        } else {                         // c == 62: drain stageB(63)
            asm volatile("s_waitcnt vmcnt(0) lgkmcnt(0)" ::: "memory");
        }
        BAR();                           // buf[(c+1)&1] published
    }

    const float beta = beta_p[0];
#pragma unroll
    for (int i = 0; i < 2; ++i) {
#pragma unroll
        for (int reg = 0; reg < 16; ++reg) {
            const int rr = (reg & 3) + 8 * (reg >> 2) + 4 * lh;
            const int b = b0 + wy * 64 + i * 32 + rr;
            const float cb = beta * (1.0f / 512.0f) * sqrtf(na2[b]);
            float s = 0.f;
#pragma unroll
            for (int j = 0; j < 2; ++j) {
                const int m = m0 + wx * 64 + j * 32 + ln;
                const size_t po = ((size_t)(b >> 5) * 32 + (m >> 4)) * 512
                                + (((size_t)(m >> 3) & 1) << 8) + ((b & 31) << 3) + (m & 7);
                const size_t yi = (size_t)b * Msz + m;
                float vold = (float)vh[po];
                float val = y[yi] - beta * acc[i][j][reg] + cb * vold;
                vh[po] = (_Float16)val;
                s = fmaf(val, val, s);
            }
            s += __shfl_down(s, 16, 32);
            s += __shfl_down(s, 8, 32);
            s += __shfl_down(s, 4, 32);
            s += __shfl_down(s, 2, 32);
            s += __shfl_down(s, 1, 32);
            if (ln == 0) atomicAdd(&t2[b], s);
        }
    }
}

extern "C" void kernel_launch(void* const* d_in, const int* in_sizes, int n_in,
                              void* d_out, int out_size, void* d_ws, size_t ws_size,
                              hipStream_t stream) {
    (void)in_sizes; (void)n_in; (void)out_size; (void)ws_size;
    const float* batch   = (const float*)d_in[0];   // [B, M]
    const float* D       = (const float*)d_in[1];   // [M, N]
    const float* gamma_p = (const float*)d_in[2];   // scalar
    const float* beta_p  = (const float*)d_in[3];   // scalar

    float* out = (float*)d_out;     // fp32 plain, written only by LAST gemm1

    // workspace (~90 MB): vh | Dph | Dtph | alphaH | t2s | na2s
    _Float16* vh     = (_Float16*)d_ws;             // [B*M] permuted, single plane
    _Float16* Dph    = vh + (size_t)Bsz * Msz;      // [M*N] permuted (gemm2 B), f16
    _Float16* Dtph   = Dph + (size_t)Msz * Nsz;     // [N*M] permuted (gemm1 B), f16
    _Float16* alphaH = Dtph + (size_t)Msz * Nsz;    // [B*N] plain f16 alpha carry
    float*    t2s    = (float*)(alphaH + (size_t)Bsz * Nsz);   // [10][Bsz] sum v^2
    float*    na2s   = t2s + 10 * Bsz;                          // [10][Bsz] sum alpha^2

    // zero t2 slabs 1..9 + na2 slabs 0..9 (contiguous 19*Bsz floats)
    zero_kernel<<<19 * Bsz / 1024, 256, 0, stream>>>((float4*)(t2s + Bsz));
    convD_kernel<<<dim3(Nsz / 64, Msz / 64), 256, 0, stream>>>(D, Dph, Dtph);
    init_kernel<<<Bsz / 4, 256, 0, stream>>>(batch, vh, t2s);   // writes t2 slab 0

    for (int it = 0; it < 10; ++it) {
        if (it == 0)
            gemm1_kernel<1, 0><<<2048, 256, 0, stream>>>(vh, Dtph,
                    t2s + (size_t)it * Bsz, alphaH, out, na2s + (size_t)it * Bsz,
                    beta_p, gamma_p);
        else if (it == 9)
            gemm1_kernel<0, 1><<<2048, 256, 0, stream>>>(vh, Dtph,
                    t2s + (size_t)it * Bsz, alphaH, out, na2s + (size_t)it * Bsz,
                    beta_p, gamma_p);
        else
            gemm1_kernel<0, 0><<<2048, 256, 0, stream>>>(vh, Dtph,
                    t2s + (size_t)it * Bsz, alphaH, out, na2s + (size_t)it * Bsz,
                    beta_p, gamma_p);
        if (it < 9) {   // last iteration's new_v is unused by the reference output
            gemm2_kernel<<<512, 256, 0, stream>>>(alphaH, Dph,
                                                  na2s + (size_t)it * Bsz,
                                                  batch, vh,
                                                  t2s + (size_t)(it + 1) * Bsz,
                                                  beta_p);
        }
    }
}